// Round 16
// baseline (154.731 us; speedup 1.0000x reference)
//
#include <hip/hip_runtime.h>
#include <hip/hip_bf16.h>

typedef __bf16 bf16x8 __attribute__((ext_vector_type(8)));
typedef float f32x4 __attribute__((ext_vector_type(4)));
typedef float f32x16 __attribute__((ext_vector_type(16)));
typedef unsigned short u16;
typedef unsigned int u32;
typedef u16 u16x8 __attribute__((ext_vector_type(8)));
typedef u32 u32x4 __attribute__((ext_vector_type(4)));

#define SM_SCALE 0.1803368801111244f  // (1/8) * log2(e), folded into Q

// raw hardware transcendentals (args in safe range; no OCML guards)
#define FEXP2(x) __builtin_amdgcn_exp2f(x)
#define FLOG2(x) __builtin_amdgcn_logf(x)

// f32 -> bf16 round-to-nearest-even
__device__ inline u16 tobf(float f) {
  u32 u = __builtin_bit_cast(u32, f);
  u32 r = (u + 0x7fffu + ((u >> 16) & 1u)) >> 16;
  return (u16)r;
}

__device__ inline float frombf(u16 h) {
  return __builtin_bit_cast(float, (u32)h << 16);
}

__device__ inline void gload_lds16(const void* g, void* lds) {
  __builtin_amdgcn_global_load_lds(
      (const __attribute__((address_space(1))) u32*)g,
      (__attribute__((address_space(3))) u32*)lds, 16, 0, 0);
}

template <int N>
__device__ __forceinline__ void wait_vmcnt() {
  if constexpr (N == 0)
    asm volatile("s_waitcnt vmcnt(0)" ::: "memory");
  else if constexpr (N == 5)
    asm volatile("s_waitcnt vmcnt(5)" ::: "memory");
  else if constexpr (N == 7)
    asm volatile("s_waitcnt vmcnt(7)" ::: "memory");
}

// ---------------- fused prep: convert x + transpose both weights ----------
__device__ __forceinline__ void transpose_body(const float* __restrict__ in,
                                               u16* __restrict__ out, int K,
                                               int N, int bxg, int tid) {
  __shared__ float tile[32][33];
  int nbx = N >> 5;
  int bx = bxg % nbx, by = bxg / nbx;
  int k0 = by << 5, n0 = bx << 5;
  int tx = tid & 31, ty = tid >> 5;
#pragma unroll
  for (int j = 0; j < 4; ++j) {
    int row = ty + j * 8;
    tile[row][tx] = in[(size_t)(k0 + row) * N + n0 + tx];
  }
  __syncthreads();
#pragma unroll
  for (int j = 0; j < 4; ++j) {
    int row = ty + j * 8;
    out[(size_t)(n0 + row) * K + k0 + tx] = tobf(tile[tx][row]);
  }
}

__global__ __launch_bounds__(256) void prep_kernel(
    const float* __restrict__ x, u16* __restrict__ xb,
    const float* __restrict__ wa, u16* __restrict__ wat,
    const float* __restrict__ wp, u16* __restrict__ wpt) {
  const int b = blockIdx.x, tid = threadIdx.x;
  if (b < 2048) {
    int i = b * 256 + tid;  // 2048*256*8 == 4096*1024 exactly
    const float4* p = (const float4*)x + (size_t)i * 2;
    float4 a = p[0], c = p[1];
    u16x8 v;
    v[0] = tobf(a.x); v[1] = tobf(a.y); v[2] = tobf(a.z); v[3] = tobf(a.w);
    v[4] = tobf(c.x); v[5] = tobf(c.y); v[6] = tobf(c.z); v[7] = tobf(c.w);
    *(u16x8*)(xb + (size_t)i * 8) = v;
  } else if (b < 5120) {
    transpose_body(wa, wat, 1024, 3072, b - 2048, tid);
  } else {
    transpose_body(wp, wpt, 1024, 1024, b - 5120, tid);
  }
}

// ---------------- GEMM: C[M,N] = A[M,K] * Bt[N,K]^T  (bf16 in, f32 acc) ---
// BM=128, BN in {192, 64}. 2-buffer staging with COUNTED vmcnt (no drains).
template <int EPI, int BN>
__global__ __launch_bounds__(256) void gemm_bt(
    const u16* __restrict__ A, const u16* __restrict__ Bt,
    const float* __restrict__ bias,
    u16* __restrict__ o0, u16* __restrict__ o1, u16* __restrict__ o2,
    float* __restrict__ fo, int M, int N, int K) {
  constexpr int NF = BN / 32;
  __shared__ __align__(16) u16 As[2][128 * 64];
  __shared__ __align__(16) u16 Bs[2][BN * 64];
  const int tid = threadIdx.x;
  const int lane = tid & 63;
  const int wave = tid >> 6;
  const int nbn = N / BN;
  int bid = (int)blockIdx.x;
  const int cpx = (int)gridDim.x >> 3;
  bid = (bid & 7) * cpx + (bid >> 3);
  const int bm = bid / nbn, bn = bid % nbn;
  const int m0 = bm << 7, n0 = bn * BN;
  const int wr = wave >> 1, wc = wave & 1;
  const int r15 = lane & 15, g = lane >> 4;

  f32x4 acc[4][NF] = {};

#define GSTAGE(buf, kt)                                                    \
  do {                                                                     \
    _Pragma("unroll")                                                      \
    for (int j = 0; j < 4; ++j) {                                          \
      int c = j * 4 + wave;                                                \
      int byte0 = c * 1024 + lane * 16;                                    \
      int row = byte0 >> 7;                                                \
      int colb = (byte0 & 127) ^ ((row & 7) << 4);                         \
      gload_lds16(A + (size_t)(m0 + row) * K + (kt) * 64 + (colb >> 1),    \
                  (char*)As[(buf)] + c * 1024);                            \
    }                                                                      \
    _Pragma("unroll")                                                      \
    for (int j = 0; j < NF; ++j) {                                         \
      int c = j * 4 + wave;                                                \
      int byte0 = c * 1024 + lane * 16;                                    \
      int row = byte0 >> 7;                                                \
      int colb = (byte0 & 127) ^ ((row & 7) << 4);                         \
      gload_lds16(Bt + (size_t)(n0 + row) * K + (kt) * 64 + (colb >> 1),   \
                  (char*)Bs[(buf)] + c * 1024);                            \
    }                                                                      \
  } while (0)

  const int nkt = K >> 6;
  GSTAGE(0, 0);
  for (int kt = 0; kt < nkt; ++kt) {
    const int cur = kt & 1;
    if (kt + 1 < nkt) {
      GSTAGE(cur ^ 1, kt + 1);
      wait_vmcnt<4 + NF>();  // tile kt landed; tile kt+1 stays in flight
    } else {
      wait_vmcnt<0>();
    }
    __builtin_amdgcn_s_barrier();
#pragma unroll
    for (int kk = 0; kk < 2; ++kk) {
      bf16x8 af[4], bf[NF];
#pragma unroll
      for (int i = 0; i < 4; ++i) {
        int rowA = wr * 64 + i * 16 + r15;
        int ca = (kk * 64 + 16 * g) ^ ((rowA & 7) << 4);
        af[i] = *(const bf16x8*)((const char*)As[cur] + rowA * 128 + ca);
      }
#pragma unroll
      for (int j2 = 0; j2 < NF; ++j2) {
        int rowB = wc * (BN / 2) + j2 * 16 + r15;
        int cb = (kk * 64 + 16 * g) ^ ((rowB & 7) << 4);
        bf[j2] = *(const bf16x8*)((const char*)Bs[cur] + rowB * 128 + cb);
      }
#pragma unroll
      for (int i = 0; i < 4; ++i)
#pragma unroll
        for (int j2 = 0; j2 < NF; ++j2)
          acc[i][j2] = __builtin_amdgcn_mfma_f32_16x16x32_bf16(
              af[i], bf[j2], acc[i][j2], 0, 0, 0);
    }
    if (kt + 1 < nkt) __builtin_amdgcn_s_barrier();  // protect buf[cur]
  }
#undef GSTAGE

#pragma unroll
  for (int j2 = 0; j2 < NF; ++j2) {
    const int n = n0 + wc * (BN / 2) + j2 * 16 + r15;
    const float bv = bias[n];
#pragma unroll
    for (int i = 0; i < 4; ++i) {
      const int mb = m0 + wr * 64 + i * 16 + g * 4;
      float v[4];
#pragma unroll
      for (int rr = 0; rr < 4; ++rr) v[rr] = acc[i][j2][rr] + bv;
      if (EPI == 1) {
#pragma unroll
        for (int rr = 0; rr < 4; ++rr) fo[(size_t)(mb + rr) * N + n] = v[rr];
      } else {
        const int b = mb >> 11, t = mb & 2047;
        const int sec = n >> 10, nn = n & 1023;
        const int h = nn >> 6, d = nn & 63;
        const int bh = b * 16 + h;
        if (sec == 0) {
          u16* base = o0 + ((size_t)bh * 2048 + t) * 64 + d;
#pragma unroll
          for (int rr = 0; rr < 4; ++rr) base[rr * 64] = tobf(v[rr] * SM_SCALE);
        } else if (sec == 1) {
          // kpack[bh][kt][ks=d>>4][h2][hi=(d>>3)&1][q31][e=d&7]
          u16* kb = o1 +
                    (((size_t)(bh * 32 + (t >> 6)) * 4 + (d >> 4)) * 2) * 512 +
                    ((d >> 3) & 1) * 256 + (d & 7);
          const int tb = t & 63;
#pragma unroll
          for (int rr = 0; rr < 4; ++rr) {
            int r = tb + rr;
            kb[(r >> 5) * 512 + (r & 31) * 8] = tobf(v[rr]);
          }
        } else {
          // vpack[bh][kt][ks=(t&63)>>4][d2=d>>5][hi][d31][e=t&7], 4 consec t
          const int tl = t & 63;
          u16* vb = o2 +
                    ((((size_t)(bh * 32 + (t >> 6)) * 4 + (tl >> 4)) * 2 +
                      (d >> 5)) * 512) +
                    ((tl >> 3) & 1) * 256 + (d & 31) * 8 + (tl & 7);
          u32* p = (u32*)vb;
          p[0] = (u32)tobf(v[0]) | ((u32)tobf(v[1]) << 16);
          p[1] = (u32)tobf(v[2]) | ((u32)tobf(v[3]) << 16);
        }
      }
    }
  }
}

// ---------------- causal flash attention v14: interleave + 5 waves/SIMD ---
// Block = 32 q rows x full causal KV range; 4 free-running waves stride-4
// interleave KV tiles. K/V frags loaded in 2 batches of 4 and cvt/permlane/
// PV interleaved per-ks group to cut peak VGPR; merge partials deposited as
// NORMALIZED bf16 (y_h, Mw = m + log2 l) -> LDS 17.4 KB. launch_bounds
// (256,5) targets 5 blocks/CU = 5 waves/SIMD.
__global__ __launch_bounds__(256, 5) void attn_kernel(
    const u16* __restrict__ qb, const u16* __restrict__ kpk,
    const u16* __restrict__ vpk, u16* __restrict__ yb) {
  __shared__ u32 OfU[4 * 1056];   // [wave][q31][33] u32 (2 bf16 each)
  __shared__ float Mw[4][32];
  const int tid = threadIdx.x;
  const int lane = tid & 63;
  const int kw = tid >> 6;                      // wave = kv interleave slot
  const int q31 = lane & 31, hi = lane >> 5;
  const int bx = blockIdx.x;
  const int cq = 63 - (bx >> 5);                // heavy chunks first
  const int bh = bx & 31;
  const int q0 = cq * 32;                       // block's first q row
  const int qg = q0 + q31;                      // this lane's q row
  const int ktEnd = ((q0 + 31) >> 6) + 1;       // causal tile bound

  // Q fragments: lane holds Q[qg][d = ks*16 + 8*hi .. +8), ks=0..3
  const u16* qrow = qb + ((size_t)bh * 2048 + qg) * 64;
  bf16x8 aq[4];
#pragma unroll
  for (int ks = 0; ks < 4; ++ks)
    aq[ks] = *(const bf16x8*)(qrow + ks * 16 + 8 * hi);

  f32x16 o0 = {}, o1 = {};      // O^T: lane q=q31; d=(r&3)+8(r>>2)+4hi (+32)
  float m = -INFINITY, l = 0.f; // per-lane (per-q-row) softmax state

  // frag-pack bases: per (bh,kt) block = 4096 u16 (8 frags x 512)
  const u16* kbh = kpk + (size_t)bh * 32 * 4096 + lane * 8;
  const u16* vbh = vpk + (size_t)bh * 32 * 4096 + lane * 8;

  for (int kt = kw; kt < ktEnd; kt += 4) {
    const u16* kp = kbh + (size_t)kt * 4096;
    const u16* vp = vbh + (size_t)kt * 4096;

    f32x16 s0 = {}, s1 = {};
    {  // QK first half: ks 0,1 (frags 0..3)
      bf16x8 k0 = *(const bf16x8*)(kp);
      bf16x8 k1 = *(const bf16x8*)(kp + 512);
      bf16x8 k2 = *(const bf16x8*)(kp + 1024);
      bf16x8 k3 = *(const bf16x8*)(kp + 1536);
      __builtin_amdgcn_s_setprio(1);
      s0 = __builtin_amdgcn_mfma_f32_32x32x16_bf16(k0, aq[0], s0, 0, 0, 0);
      s1 = __builtin_amdgcn_mfma_f32_32x32x16_bf16(k1, aq[0], s1, 0, 0, 0);
      s0 = __builtin_amdgcn_mfma_f32_32x32x16_bf16(k2, aq[1], s0, 0, 0, 0);
      s1 = __builtin_amdgcn_mfma_f32_32x32x16_bf16(k3, aq[1], s1, 0, 0, 0);
      __builtin_amdgcn_s_setprio(0);
    }
    {  // QK second half: ks 2,3 (frags 4..7)
      bf16x8 k0 = *(const bf16x8*)(kp + 2048);
      bf16x8 k1 = *(const bf16x8*)(kp + 2560);
      bf16x8 k2 = *(const bf16x8*)(kp + 3072);
      bf16x8 k3 = *(const bf16x8*)(kp + 3584);
      __builtin_amdgcn_s_setprio(1);
      s0 = __builtin_amdgcn_mfma_f32_32x32x16_bf16(k0, aq[2], s0, 0, 0, 0);
      s1 = __builtin_amdgcn_mfma_f32_32x32x16_bf16(k1, aq[2], s1, 0, 0, 0);
      s0 = __builtin_amdgcn_mfma_f32_32x32x16_bf16(k2, aq[3], s0, 0, 0, 0);
      s1 = __builtin_amdgcn_mfma_f32_32x32x16_bf16(k3, aq[3], s1, 0, 0, 0);
      __builtin_amdgcn_s_setprio(0);
    }

    // V first batch (frags 0..3, for PV groups 0,1) — hides under softmax
    bf16x8 vfA0 = *(const bf16x8*)(vp);
    bf16x8 vfA1 = *(const bf16x8*)(vp + 512);
    bf16x8 vfA2 = *(const bf16x8*)(vp + 1024);
    bf16x8 vfA3 = *(const bf16x8*)(vp + 1536);

    // causal mask (diagonal tiles only; wave-uniform branch)
    if (kt * 64 + 63 > q0) {
      const int thr = qg - kt * 64;
#pragma unroll
      for (int r = 0; r < 16; ++r) {
        const int off = (r & 3) + 8 * (r >> 2) + 4 * hi;
        if (off > thr) s0[r] = -INFINITY;
        if (off + 32 > thr) s1[r] = -INFINITY;
      }
    }
    // tree max over 32 in-lane values
    f32x16 mx;
#pragma unroll
    for (int r = 0; r < 16; ++r) mx[r] = fmaxf(s0[r], s1[r]);
#pragma unroll
    for (int st = 8; st >= 1; st >>= 1)
#pragma unroll
      for (int r = 0; r < st; ++r) mx[r] = fmaxf(mx[r], mx[r + st]);
    float mt = fmaxf(mx[0], __shfl_xor(mx[0], 32, 64));

    if (kt == kw) {
      m = mt;  // wave's first tile: 64*kw <= q0 guarantees mt finite
    } else if (__any(mt > m + 8.f)) {
      float mnew = fmaxf(m, mt);
      float alpha = FEXP2(m - mnew);
      m = mnew;
      l *= alpha;
#pragma unroll
      for (int r = 0; r < 16; ++r) {
        o0[r] *= alpha;
        o1[r] *= alpha;
      }
    }
#pragma unroll
    for (int r = 0; r < 16; ++r) {
      s0[r] = FEXP2(s0[r] - m);
      s1[r] = FEXP2(s1[r] - m);
    }
    {
      float la = 0.f, lb = 0.f, lc2 = 0.f, ld = 0.f;
#pragma unroll
      for (int r = 0; r < 16; r += 2) {
        la += s0[r];
        lb += s0[r + 1];
        lc2 += s1[r];
        ld += s1[r + 1];
      }
      l += (la + lb) + (lc2 + ld);
    }
    // V second batch (frags 4..7, PV groups 2,3) — hides under PV g0/g1
    bf16x8 vfB0 = *(const bf16x8*)(vp + 2048);
    bf16x8 vfB1 = *(const bf16x8*)(vp + 2560);
    bf16x8 vfB2 = *(const bf16x8*)(vp + 3072);
    bf16x8 vfB3 = *(const bf16x8*)(vp + 3584);

    // per-ks group: cvt_pk -> permlane -> PV (only 4 W words live)
#define PVG(SV, BASE, VA, VB)                                              \
  do {                                                                     \
    u32 Wk0, Wk1, Wk2, Wk3;                                                \
    asm("v_cvt_pk_bf16_f32 %0, %1, %2"                                     \
        : "=v"(Wk0) : "v"(SV[(BASE) + 0]), "v"(SV[(BASE) + 1]));           \
    asm("v_cvt_pk_bf16_f32 %0, %1, %2"                                     \
        : "=v"(Wk1) : "v"(SV[(BASE) + 2]), "v"(SV[(BASE) + 3]));           \
    asm("v_cvt_pk_bf16_f32 %0, %1, %2"                                     \
        : "=v"(Wk2) : "v"(SV[(BASE) + 4]), "v"(SV[(BASE) + 5]));           \
    asm("v_cvt_pk_bf16_f32 %0, %1, %2"                                     \
        : "=v"(Wk3) : "v"(SV[(BASE) + 6]), "v"(SV[(BASE) + 7]));           \
    asm("v_permlane32_swap_b32 %0, %1" : "+v"(Wk0), "+v"(Wk2));            \
    asm("v_permlane32_swap_b32 %0, %1" : "+v"(Wk1), "+v"(Wk3));            \
    u32x4 pwv = {Wk0, Wk1, Wk2, Wk3};                                      \
    bf16x8 pf = __builtin_bit_cast(bf16x8, pwv);                           \
    __builtin_amdgcn_s_setprio(1);                                         \
    o0 = __builtin_amdgcn_mfma_f32_32x32x16_bf16(VA, pf, o0, 0, 0, 0);     \
    o1 = __builtin_amdgcn_mfma_f32_32x32x16_bf16(VB, pf, o1, 0, 0, 0);     \
    __builtin_amdgcn_s_setprio(0);                                         \
  } while (0)

    PVG(s0, 0, vfA0, vfA1);
    PVG(s0, 8, vfA2, vfA3);
    PVG(s1, 0, vfB0, vfB1);
    PVG(s1, 8, vfB2, vfB3);
#undef PVG
  }

  // combine partner's partial sum (other kv half, same q)
  l += __shfl_xor(l, 32, 64);

  // normalized bf16 deposit + log-weight
  float invl, MwV;
  if (l > 0.f) {
    invl = 1.0f / l;
    MwV = m + FLOG2(l);
  } else {
    invl = 0.f;
    MwV = -INFINITY;
  }
  u32* OfW = OfU + kw * 1056 + q31 * 33;
#pragma unroll
  for (int r = 0; r < 16; r += 2) {
    const int d = (r & 3) + 8 * (r >> 2) + 4 * hi;
    OfW[d >> 1] =
        (u32)tobf(o0[r] * invl) | ((u32)tobf(o0[r + 1] * invl) << 16);
    OfW[(d + 32) >> 1] =
        (u32)tobf(o1[r] * invl) | ((u32)tobf(o1[r + 1] * invl) << 16);
  }
  if (hi == 0) Mw[kw][q31] = MwV;
  __syncthreads();

  // merge: thread -> q = tid>>3, u32 cols c0..c0+3 (8 bf16 = d0..d0+7)
  const int q = tid >> 3, c0 = (tid & 7) * 4;
  const float m0v = Mw[0][q], m1v = Mw[1][q], m2v = Mw[2][q], m3v = Mw[3][q];
  const float Mx = fmaxf(fmaxf(m0v, m1v), fmaxf(m2v, m3v));
  const float w0 = FEXP2(m0v - Mx), w1 = FEXP2(m1v - Mx);
  const float w2 = FEXP2(m2v - Mx), w3 = FEXP2(m3v - Mx);
  const float invW = 1.0f / (w0 + w1 + w2 + w3);
  const int b = bh >> 4, hd = bh & 15;
  u32* dst = (u32*)(yb + ((size_t)b * 2048 + q0 + q) * 1024 + hd * 64) + c0;
  const int base = q * 33 + c0;
#pragma unroll
  for (int cc = 0; cc < 4; ++cc) {
    const u32 v0 = OfU[0 * 1056 + base + cc];
    const u32 v1 = OfU[1 * 1056 + base + cc];
    const u32 v2 = OfU[2 * 1056 + base + cc];
    const u32 v3 = OfU[3 * 1056 + base + cc];
    float lo = frombf((u16)v0) * w0 + frombf((u16)v1) * w1 +
               frombf((u16)v2) * w2 + frombf((u16)v3) * w3;
    float hi2 = frombf((u16)(v0 >> 16)) * w0 + frombf((u16)(v1 >> 16)) * w1 +
                frombf((u16)(v2 >> 16)) * w2 + frombf((u16)(v3 >> 16)) * w3;
    dst[cc] = (u32)tobf(lo * invW) | ((u32)tobf(hi2 * invW) << 16);
  }
}

extern "C" void kernel_launch(void* const* d_in, const int* in_sizes, int n_in,
                              void* d_out, int out_size, void* d_ws,
                              size_t ws_size, hipStream_t stream) {
  const float* x = (const float*)d_in[0];
  const float* w_attn = (const float*)d_in[1];
  const float* b_attn = (const float*)d_in[2];
  const float* w_proj = (const float*)d_in[3];
  const float* b_proj = (const float*)d_in[4];
  float* out = (float*)d_out;
  char* ws = (char*)d_ws;

  u16* xb = (u16*)ws;                          // 8 MB [4096][1024] (dead after GEMM1)
  u16* wat = (u16*)(ws + (8ull << 20));        // 6 MB (dead after GEMM1)
  u16* wpt = (u16*)(ws + (14ull << 20));       // 2 MB (alive until GEMM2)
  u16* qbuf = (u16*)(ws + (16ull << 20));      // 8 MB [bh][t][64] (q pre-scaled)
  u16* kpk = (u16*)(ws + (24ull << 20));       // 8 MB frag-packed K
  u16* vpk = (u16*)(ws + (32ull << 20));       // 8 MB frag-packed V
  u16* yb = (u16*)(ws + (40ull << 20));        // 8 MB [4096][1024]

  prep_kernel<<<6144, 256, 0, stream>>>(x, xb, w_attn, wat, w_proj, wpt);
  gemm_bt<0, 192><<<32 * 16, 256, 0, stream>>>(xb, wat, b_attn, qbuf, kpk,
                                               vpk, nullptr, 4096, 3072, 1024);
  attn_kernel<<<2048, 256, 0, stream>>>(qbuf, kpk, vpk, yb);
  gemm_bt<1, 64><<<32 * 16, 256, 0, stream>>>(yb, wpt, b_proj, nullptr,
                                              nullptr, nullptr, out, 4096,
                                              1024, 1024);
}

// Round 17
// 97.635 us; speedup vs baseline: 1.5848x; 1.5848x over previous
//
#include <hip/hip_runtime.h>
#include <hip/hip_bf16.h>

typedef __bf16 bf16x8 __attribute__((ext_vector_type(8)));
typedef float f32x4 __attribute__((ext_vector_type(4)));
typedef float f32x16 __attribute__((ext_vector_type(16)));
typedef unsigned short u16;
typedef unsigned int u32;
typedef u16 u16x8 __attribute__((ext_vector_type(8)));
typedef u32 u32x4 __attribute__((ext_vector_type(4)));

#define SM_SCALE 0.1803368801111244f  // (1/8) * log2(e), folded into Q

// raw hardware transcendentals (args in safe range; no OCML guards)
#define FEXP2(x) __builtin_amdgcn_exp2f(x)

// f32 -> bf16 round-to-nearest-even
__device__ inline u16 tobf(float f) {
  u32 u = __builtin_bit_cast(u32, f);
  u32 r = (u + 0x7fffu + ((u >> 16) & 1u)) >> 16;
  return (u16)r;
}

__device__ inline void gload_lds16(const void* g, void* lds) {
  __builtin_amdgcn_global_load_lds(
      (const __attribute__((address_space(1))) u32*)g,
      (__attribute__((address_space(3))) u32*)lds, 16, 0, 0);
}

template <int N>
__device__ __forceinline__ void wait_vmcnt() {
  if constexpr (N == 0)
    asm volatile("s_waitcnt vmcnt(0)" ::: "memory");
  else if constexpr (N == 5)
    asm volatile("s_waitcnt vmcnt(5)" ::: "memory");
  else if constexpr (N == 7)
    asm volatile("s_waitcnt vmcnt(7)" ::: "memory");
}

// ---------------- fused prep: convert x + transpose both weights ----------
__device__ __forceinline__ void transpose_body(const float* __restrict__ in,
                                               u16* __restrict__ out, int K,
                                               int N, int bxg, int tid) {
  __shared__ float tile[32][33];
  int nbx = N >> 5;
  int bx = bxg % nbx, by = bxg / nbx;
  int k0 = by << 5, n0 = bx << 5;
  int tx = tid & 31, ty = tid >> 5;
#pragma unroll
  for (int j = 0; j < 4; ++j) {
    int row = ty + j * 8;
    tile[row][tx] = in[(size_t)(k0 + row) * N + n0 + tx];
  }
  __syncthreads();
#pragma unroll
  for (int j = 0; j < 4; ++j) {
    int row = ty + j * 8;
    out[(size_t)(n0 + row) * K + k0 + tx] = tobf(tile[tx][row]);
  }
}

__global__ __launch_bounds__(256) void prep_kernel(
    const float* __restrict__ x, u16* __restrict__ xb,
    const float* __restrict__ wa, u16* __restrict__ wat,
    const float* __restrict__ wp, u16* __restrict__ wpt) {
  const int b = blockIdx.x, tid = threadIdx.x;
  if (b < 2048) {
    int i = b * 256 + tid;  // 2048*256*8 == 4096*1024 exactly
    const float4* p = (const float4*)x + (size_t)i * 2;
    float4 a = p[0], c = p[1];
    u16x8 v;
    v[0] = tobf(a.x); v[1] = tobf(a.y); v[2] = tobf(a.z); v[3] = tobf(a.w);
    v[4] = tobf(c.x); v[5] = tobf(c.y); v[6] = tobf(c.z); v[7] = tobf(c.w);
    *(u16x8*)(xb + (size_t)i * 8) = v;
  } else if (b < 5120) {
    transpose_body(wa, wat, 1024, 3072, b - 2048, tid);
  } else {
    transpose_body(wp, wpt, 1024, 1024, b - 5120, tid);
  }
}

// ---------------- GEMM: C[M,N] = A[M,K] * Bt[N,K]^T  (bf16 in, f32 acc) ---
// BM=128, BN in {192, 64}. 2-buffer staging with COUNTED vmcnt (no drains).
template <int EPI, int BN>
__global__ __launch_bounds__(256) void gemm_bt(
    const u16* __restrict__ A, const u16* __restrict__ Bt,
    const float* __restrict__ bias,
    u16* __restrict__ o0, u16* __restrict__ o1, u16* __restrict__ o2,
    float* __restrict__ fo, int M, int N, int K) {
  constexpr int NF = BN / 32;
  __shared__ __align__(16) u16 As[2][128 * 64];
  __shared__ __align__(16) u16 Bs[2][BN * 64];
  const int tid = threadIdx.x;
  const int lane = tid & 63;
  const int wave = tid >> 6;
  const int nbn = N / BN;
  int bid = (int)blockIdx.x;
  const int cpx = (int)gridDim.x >> 3;
  bid = (bid & 7) * cpx + (bid >> 3);
  const int bm = bid / nbn, bn = bid % nbn;
  const int m0 = bm << 7, n0 = bn * BN;
  const int wr = wave >> 1, wc = wave & 1;
  const int r15 = lane & 15, g = lane >> 4;

  f32x4 acc[4][NF] = {};

#define GSTAGE(buf, kt)                                                    \
  do {                                                                     \
    _Pragma("unroll")                                                      \
    for (int j = 0; j < 4; ++j) {                                          \
      int c = j * 4 + wave;                                                \
      int byte0 = c * 1024 + lane * 16;                                    \
      int row = byte0 >> 7;                                                \
      int colb = (byte0 & 127) ^ ((row & 7) << 4);                         \
      gload_lds16(A + (size_t)(m0 + row) * K + (kt) * 64 + (colb >> 1),    \
                  (char*)As[(buf)] + c * 1024);                            \
    }                                                                      \
    _Pragma("unroll")                                                      \
    for (int j = 0; j < NF; ++j) {                                         \
      int c = j * 4 + wave;                                                \
      int byte0 = c * 1024 + lane * 16;                                    \
      int row = byte0 >> 7;                                                \
      int colb = (byte0 & 127) ^ ((row & 7) << 4);                         \
      gload_lds16(Bt + (size_t)(n0 + row) * K + (kt) * 64 + (colb >> 1),   \
                  (char*)Bs[(buf)] + c * 1024);                            \
    }                                                                      \
  } while (0)

  const int nkt = K >> 6;
  GSTAGE(0, 0);
  for (int kt = 0; kt < nkt; ++kt) {
    const int cur = kt & 1;
    if (kt + 1 < nkt) {
      GSTAGE(cur ^ 1, kt + 1);
      wait_vmcnt<4 + NF>();  // tile kt landed; tile kt+1 stays in flight
    } else {
      wait_vmcnt<0>();
    }
    __builtin_amdgcn_s_barrier();
#pragma unroll
    for (int kk = 0; kk < 2; ++kk) {
      bf16x8 af[4], bf[NF];
#pragma unroll
      for (int i = 0; i < 4; ++i) {
        int rowA = wr * 64 + i * 16 + r15;
        int ca = (kk * 64 + 16 * g) ^ ((rowA & 7) << 4);
        af[i] = *(const bf16x8*)((const char*)As[cur] + rowA * 128 + ca);
      }
#pragma unroll
      for (int j2 = 0; j2 < NF; ++j2) {
        int rowB = wc * (BN / 2) + j2 * 16 + r15;
        int cb = (kk * 64 + 16 * g) ^ ((rowB & 7) << 4);
        bf[j2] = *(const bf16x8*)((const char*)Bs[cur] + rowB * 128 + cb);
      }
#pragma unroll
      for (int i = 0; i < 4; ++i)
#pragma unroll
        for (int j2 = 0; j2 < NF; ++j2)
          acc[i][j2] = __builtin_amdgcn_mfma_f32_16x16x32_bf16(
              af[i], bf[j2], acc[i][j2], 0, 0, 0);
    }
    if (kt + 1 < nkt) __builtin_amdgcn_s_barrier();  // protect buf[cur]
  }
#undef GSTAGE

#pragma unroll
  for (int j2 = 0; j2 < NF; ++j2) {
    const int n = n0 + wc * (BN / 2) + j2 * 16 + r15;
    const float bv = bias[n];
#pragma unroll
    for (int i = 0; i < 4; ++i) {
      const int mb = m0 + wr * 64 + i * 16 + g * 4;
      float v[4];
#pragma unroll
      for (int rr = 0; rr < 4; ++rr) v[rr] = acc[i][j2][rr] + bv;
      if (EPI == 1) {
#pragma unroll
        for (int rr = 0; rr < 4; ++rr) fo[(size_t)(mb + rr) * N + n] = v[rr];
      } else {
        const int b = mb >> 11, t = mb & 2047;
        const int sec = n >> 10, nn = n & 1023;
        const int h = nn >> 6, d = nn & 63;
        const int bh = b * 16 + h;
        if (sec == 0) {
          u16* base = o0 + ((size_t)bh * 2048 + t) * 64 + d;
#pragma unroll
          for (int rr = 0; rr < 4; ++rr) base[rr * 64] = tobf(v[rr] * SM_SCALE);
        } else if (sec == 1) {
          // kpack[bh][kt][ks=d>>4][h2][hi=(d>>3)&1][q31][e=d&7]
          u16* kb = o1 +
                    (((size_t)(bh * 32 + (t >> 6)) * 4 + (d >> 4)) * 2) * 512 +
                    ((d >> 3) & 1) * 256 + (d & 7);
          const int tb = t & 63;
#pragma unroll
          for (int rr = 0; rr < 4; ++rr) {
            int r = tb + rr;
            kb[(r >> 5) * 512 + (r & 31) * 8] = tobf(v[rr]);
          }
        } else {
          // vpack[bh][kt][ks=(t&63)>>4][d2=d>>5][hi][d31][e=t&7], 4 consec t
          const int tl = t & 63;
          u16* vb = o2 +
                    ((((size_t)(bh * 32 + (t >> 6)) * 4 + (tl >> 4)) * 2 +
                      (d >> 5)) * 512) +
                    ((tl >> 3) & 1) * 256 + (d & 31) * 8 + (tl & 7);
          u32* p = (u32*)vb;
          p[0] = (u32)tobf(v[0]) | ((u32)tobf(v[1]) << 16);
          p[1] = (u32)tobf(v[2]) | ((u32)tobf(v[3]) << 16);
        }
      }
    }
  }
}

// ---------------- causal flash attention v13: in-block KV-interleave ------
// Block = 32 q rows x full causal KV range; 4 free-running waves stride-4
// interleave the KV tiles (wave kw: kt = kw, kw+4, ...). L2-direct body,
// no in-loop barriers, raw exp2. One end-of-kernel LDS merge (4-way
// log-sum-exp blend) writes yb directly.
__global__ __launch_bounds__(256) void attn_kernel(
    const u16* __restrict__ qb, const u16* __restrict__ kpk,
    const u16* __restrict__ vpk, u16* __restrict__ yb) {
  __shared__ float Of[4][32 * 67];  // stride 67: <=2-way bank alias (free)
  __shared__ float Ml[4][32], Ll[4][32];
  const int tid = threadIdx.x;
  const int lane = tid & 63;
  const int kw = tid >> 6;                      // wave = kv interleave slot
  const int q31 = lane & 31, hi = lane >> 5;
  const int bx = blockIdx.x;
  const int cq = 63 - (bx >> 5);                // heavy chunks first
  const int bh = bx & 31;
  const int q0 = cq * 32;                       // block's first q row
  const int qg = q0 + q31;                      // this lane's q row
  const int ktEnd = ((q0 + 31) >> 6) + 1;       // causal tile bound

  // Q fragments: lane holds Q[qg][d = ks*16 + 8*hi .. +8), ks=0..3
  const u16* qrow = qb + ((size_t)bh * 2048 + qg) * 64;
  bf16x8 aq[4];
#pragma unroll
  for (int ks = 0; ks < 4; ++ks)
    aq[ks] = *(const bf16x8*)(qrow + ks * 16 + 8 * hi);

  f32x16 o0 = {}, o1 = {};      // O^T: lane q=q31; d=(r&3)+8(r>>2)+4hi (+32)
  float m = -INFINITY, l = 0.f; // per-lane (per-q-row) softmax state

  // frag-pack bases: per (bh,kt) block = 4096 u16 (8 frags x 512)
  const u16* kbh = kpk + (size_t)bh * 32 * 4096 + lane * 8;
  const u16* vbh = vpk + (size_t)bh * 32 * 4096 + lane * 8;

  for (int kt = kw; kt < ktEnd; kt += 4) {
    const u16* kp = kbh + (size_t)kt * 4096;
    const u16* vp = vbh + (size_t)kt * 4096;

    // K frags: (ks,h2) at kp + (ks*2+h2)*512 — lane-linear 1KB loads
    bf16x8 kf[8];
#pragma unroll
    for (int j = 0; j < 8; ++j) kf[j] = *(const bf16x8*)(kp + j * 512);

    f32x16 s0 = {}, s1 = {};
    __builtin_amdgcn_s_setprio(1);
#pragma unroll
    for (int ks = 0; ks < 4; ++ks) {
      s0 = __builtin_amdgcn_mfma_f32_32x32x16_bf16(kf[2 * ks], aq[ks], s0, 0, 0, 0);
      s1 = __builtin_amdgcn_mfma_f32_32x32x16_bf16(kf[2 * ks + 1], aq[ks], s1, 0, 0, 0);
    }
    __builtin_amdgcn_s_setprio(0);

    // causal mask (diagonal tiles only; wave-uniform branch)
    if (kt * 64 + 63 > q0) {
      const int thr = qg - kt * 64;
#pragma unroll
      for (int r = 0; r < 16; ++r) {
        const int off = (r & 3) + 8 * (r >> 2) + 4 * hi;
        if (off > thr) s0[r] = -INFINITY;
        if (off + 32 > thr) s1[r] = -INFINITY;
      }
    }
    // tree max over 32 in-lane values
    f32x16 mx;
#pragma unroll
    for (int r = 0; r < 16; ++r) mx[r] = fmaxf(s0[r], s1[r]);
#pragma unroll
    for (int st = 8; st >= 1; st >>= 1)
#pragma unroll
      for (int r = 0; r < st; ++r) mx[r] = fmaxf(mx[r], mx[r + st]);
    float mt = fmaxf(mx[0], __shfl_xor(mx[0], 32, 64));

    if (kt == kw) {
      m = mt;  // wave's first tile: 64*kw <= q0 guarantees mt finite
    } else if (__any(mt > m + 8.f)) {
      float mnew = fmaxf(m, mt);
      float alpha = FEXP2(m - mnew);
      m = mnew;
      l *= alpha;
#pragma unroll
      for (int r = 0; r < 16; ++r) {
        o0[r] *= alpha;
        o1[r] *= alpha;
      }
    }
#pragma unroll
    for (int r = 0; r < 16; ++r) {
      s0[r] = FEXP2(s0[r] - m);
      s1[r] = FEXP2(s1[r] - m);
    }
    {
      float la = 0.f, lb = 0.f, lc2 = 0.f, ld = 0.f;
#pragma unroll
      for (int r = 0; r < 16; r += 2) {
        la += s0[r];
        lb += s0[r + 1];
        lc2 += s1[r];
        ld += s1[r + 1];
      }
      l += (la + lb) + (lc2 + ld);
    }
    // pack to bf16 pairs then redistribute halves across lane<32/>=32
    u32 W[16];
#pragma unroll
    for (int i2 = 0; i2 < 8; ++i2) {
      asm("v_cvt_pk_bf16_f32 %0, %1, %2"
          : "=v"(W[i2]) : "v"(s0[2 * i2]), "v"(s0[2 * i2 + 1]));
      asm("v_cvt_pk_bf16_f32 %0, %1, %2"
          : "=v"(W[8 + i2]) : "v"(s1[2 * i2]), "v"(s1[2 * i2 + 1]));
    }
#pragma unroll
    for (int b4 = 0; b4 < 16; b4 += 4) {
      asm("v_permlane32_swap_b32 %0, %1" : "+v"(W[b4]), "+v"(W[b4 + 2]));
      asm("v_permlane32_swap_b32 %0, %1" : "+v"(W[b4 + 1]), "+v"(W[b4 + 3]));
    }
    // V frags: (ks,d2) at vp + (ks*2+d2)*512
    bf16x8 vf[8];
#pragma unroll
    for (int j = 0; j < 8; ++j) vf[j] = *(const bf16x8*)(vp + j * 512);

    // PV: O^T += V^T * P^T
    __builtin_amdgcn_s_setprio(1);
#pragma unroll
    for (int ks = 0; ks < 4; ++ks) {
      u32x4 pwv = {W[4 * ks], W[4 * ks + 1], W[4 * ks + 2], W[4 * ks + 3]};
      bf16x8 pf = __builtin_bit_cast(bf16x8, pwv);
      o0 = __builtin_amdgcn_mfma_f32_32x32x16_bf16(vf[2 * ks], pf, o0, 0, 0, 0);
      o1 = __builtin_amdgcn_mfma_f32_32x32x16_bf16(vf[2 * ks + 1], pf, o1, 0, 0, 0);
    }
    __builtin_amdgcn_s_setprio(0);
  }

  // combine partner's partial sum (other kv half, same q)
  l += __shfl_xor(l, 32, 64);

  // deposit this wave's unnormalized state to LDS
  float* OfW = &Of[kw][0];
#pragma unroll
  for (int r = 0; r < 16; ++r) {
    const int d = (r & 3) + 8 * (r >> 2) + 4 * hi;
    OfW[q31 * 67 + d] = o0[r];
    OfW[q31 * 67 + d + 32] = o1[r];
  }
  if (hi == 0) {
    Ml[kw][q31] = m;
    Ll[kw][q31] = l;
  }
  __syncthreads();

  // merge: thread tid -> q = tid>>3, d-block = (tid&7)*8 (8 floats)
  const int q = tid >> 3, d0 = (tid & 7) * 8;
  const float m0 = Ml[0][q], m1 = Ml[1][q], m2 = Ml[2][q], m3 = Ml[3][q];
  const float Mx = fmaxf(fmaxf(m0, m1), fmaxf(m2, m3));
  const float w0 = FEXP2(m0 - Mx), w1 = FEXP2(m1 - Mx);
  const float w2 = FEXP2(m2 - Mx), w3 = FEXP2(m3 - Mx);
  const float L = w0 * Ll[0][q] + w1 * Ll[1][q] + w2 * Ll[2][q] + w3 * Ll[3][q];
  const float inv = 1.0f / L;
  const int b = bh >> 4, hd = bh & 15;
  u32* dst = (u32*)(yb + ((size_t)b * 2048 + q0 + q) * 1024 + hd * 64 + d0);
  const int base = q * 67 + d0;
#pragma unroll
  for (int e = 0; e < 8; e += 2) {
    float v0 = (Of[0][base + e] * w0 + Of[1][base + e] * w1 +
                Of[2][base + e] * w2 + Of[3][base + e] * w3) * inv;
    float v1 = (Of[0][base + e + 1] * w0 + Of[1][base + e + 1] * w1 +
                Of[2][base + e + 1] * w2 + Of[3][base + e + 1] * w3) * inv;
    dst[e >> 1] = (u32)tobf(v0) | ((u32)tobf(v1) << 16);
  }
}

extern "C" void kernel_launch(void* const* d_in, const int* in_sizes, int n_in,
                              void* d_out, int out_size, void* d_ws,
                              size_t ws_size, hipStream_t stream) {
  const float* x = (const float*)d_in[0];
  const float* w_attn = (const float*)d_in[1];
  const float* b_attn = (const float*)d_in[2];
  const float* w_proj = (const float*)d_in[3];
  const float* b_proj = (const float*)d_in[4];
  float* out = (float*)d_out;
  char* ws = (char*)d_ws;

  u16* xb = (u16*)ws;                          // 8 MB [4096][1024] (dead after GEMM1)
  u16* wat = (u16*)(ws + (8ull << 20));        // 6 MB (dead after GEMM1)
  u16* wpt = (u16*)(ws + (14ull << 20));       // 2 MB (alive until GEMM2)
  u16* qbuf = (u16*)(ws + (16ull << 20));      // 8 MB [bh][t][64] (q pre-scaled)
  u16* kpk = (u16*)(ws + (24ull << 20));       // 8 MB frag-packed K
  u16* vpk = (u16*)(ws + (32ull << 20));       // 8 MB frag-packed V
  u16* yb = (u16*)(ws + (40ull << 20));        // 8 MB [4096][1024]

  prep_kernel<<<6144, 256, 0, stream>>>(x, xb, w_attn, wat, w_proj, wpt);
  gemm_bt<0, 192><<<32 * 16, 256, 0, stream>>>(xb, wat, b_attn, qbuf, kpk,
                                               vpk, nullptr, 4096, 3072, 1024);
  attn_kernel<<<2048, 256, 0, stream>>>(qbuf, kpk, vpk, yb);
  gemm_bt<1, 64><<<32 * 16, 256, 0, stream>>>(yb, wpt, b_proj, nullptr,
                                              nullptr, nullptr, out, 4096,
                                              1024, 1024);
}